// Round 9
// baseline (457.439 us; speedup 1.0000x reference)
//
#include <hip/hip_runtime.h>
#include <stdint.h>

// SelfAttention B=2,S=4096,E=1024,H=1024. f32 in, f32 out, bf16 MFMA inside.
// R16: ALL GEMMs converted 16x16x32 -> 32x32x16 MFMA (2382 vs 2075 TF
//   ceiling, HALF the instruction count at 32 KFLOP/inst — the one K-loop
//   variable never tried; AITER/HK attn use 32x32 exclusively). Everything
//   else byte-identical to R15 (grids, swizzles, stage choreography, psum).
//   Fragment layouts: A/B row=lane&31, k=(lane>>5)*8+e; C/D col=lane&31,
//   row=(reg&3)+8*(reg>>2)+4*(lane>>5) [m74/m101].
// R15 (best, 414.6us): fixed-cost consolidation; scores 115us @ MfmaUtil 24%,
//   ~600-680 TF plateau across 6 schedule variants => issue/latency-starved
//   phase, not bank conflicts (0) nor HBM (31%).

typedef __bf16 bf16;
typedef __attribute__((ext_vector_type(4))) __bf16 bf16x4;
typedef __attribute__((ext_vector_type(8))) __bf16 bf16x8;
typedef __attribute__((ext_vector_type(4))) float f32x4;
typedef __attribute__((ext_vector_type(16))) float f32x16;

__device__ __forceinline__ void g2l16(const void* g, void* l) {
  __builtin_amdgcn_global_load_lds(
      (const __attribute__((address_space(1))) uint32_t*)g,
      (__attribute__((address_space(3))) uint32_t*)l, 16, 0, 0);
}

__device__ __forceinline__ f32x4 ds_read128(uint32_t addr) {
  f32x4 d;
  asm volatile("ds_read_b128 %0, %1" : "=v"(d) : "v"(addr));
  return d;
}

template <int V> struct IC { static constexpr int value = V; };
template <bool V> struct BC { static constexpr bool value = V; };

template <int N> __device__ __forceinline__ void waitvm() {
  if constexpr (N == 6) asm volatile("s_waitcnt vmcnt(6)" ::: "memory");
  else if constexpr (N == 4) asm volatile("s_waitcnt vmcnt(4)" ::: "memory");
  else if constexpr (N == 0) asm volatile("s_waitcnt vmcnt(0)" ::: "memory");
}

// ---------------- fused f32 -> bf16 converter (X + Wq|Wk|Wv) ---------------
__global__ __launch_bounds__(256) void cvt_all(
    const float* __restrict__ X, const float* __restrict__ Wq,
    const float* __restrict__ Wk, const float* __restrict__ Wv,
    bf16* __restrict__ X_bf, bf16* __restrict__ W_bf) {
  const int bid = blockIdx.x;
  const float* src;
  bf16* dst;
  int i;
  if (bid < 4096) {                       // X: 8388608 elems
    i = (bid * 256 + threadIdx.x) * 8;
    src = X; dst = X_bf;
  } else {                                // W3: 3*1048576 elems
    i = ((bid - 4096) * 256 + threadIdx.x) * 8;
    const int seg = i >> 20;
    const int off = i & 1048575;
    src = (seg == 0) ? Wq : (seg == 1) ? Wk : Wv;
    dst = W_bf;
    f32x4 a = *(const f32x4*)(src + off);
    f32x4 b = *(const f32x4*)(src + off + 4);
    bf16x8 o;
#pragma unroll
    for (int e = 0; e < 4; ++e) { o[e] = (bf16)a[e]; o[4 + e] = (bf16)b[e]; }
    *(bf16x8*)(dst + i) = o;
    return;
  }
  f32x4 a = *(const f32x4*)(src + i);
  f32x4 b = *(const f32x4*)(src + i + 4);
  bf16x8 o;
#pragma unroll
  for (int e = 0; e < 4; ++e) { o[e] = (bf16)a[e]; o[4 + e] = (bf16)b[e]; }
  *(bf16x8*)(dst + i) = o;
}

// ======================= kloop256: BM=256 x BN=256, BK=64 (scores) =========
// 32x32x16 MFMA. 8 waves 2M x 4N, wave tile 128x64 = 4x2 frags of 32x32.
// Phase q computes M-block q (rows 32q..32q+31 of wave tile): 4 ksteps x
// 2 N-frags = 8 MFMA. A: 4 ds_reads/phase; B: 8 ds_reads at q==0.
// Stage choreography / WAR edges identical to R15 (phase q reads same A rows).
template <int NT>
__device__ __forceinline__ void kloop256(
    const bf16* __restrict__ Ag, const bf16* __restrict__ Bg, const int KA,
    const int KB, bf16* lds, f32x16 (&acc)[4][2]) {
  const int tid = threadIdx.x;
  const int lane = tid & 63;
  const int wave = tid >> 6;
  const int l31 = lane & 31, hi = lane >> 5;
  const int wrow = (wave >> 2) * 128;
  const int wcol = (wave & 3) * 64;
  const int srow = tid >> 3;
  const int scol = ((tid & 7) ^ (srow & 7)) * 8;
  const int swz = l31 & 7;

  const uint32_t lds_u = (uint32_t)(uintptr_t)lds;
  const uint32_t a_l = lds_u + (uint32_t)((wrow + l31) * 128);
  const uint32_t b_l = lds_u + 32768u + (uint32_t)((wcol + l31) * 128);
  uint32_t ckk[4];
#pragma unroll
  for (int ks = 0; ks < 4; ++ks)
    ckk[ks] = (uint32_t)(((ks * 2 + hi) ^ swz) * 16);

  auto stg = [&](int t, int h) {
    bf16* base = lds + (t & 1) * 32768;
    if (h == 0) {
      const bf16* g = Bg + (size_t)srow * KB + t * 64 + scol;
      g2l16(g, base + 16384 + tid * 8);
      g2l16(g + (size_t)64 * KB, base + 16384 + tid * 8 + 4096);
    } else if (h == 1) {
      const bf16* g = Bg + (size_t)(128 + srow) * KB + t * 64 + scol;
      g2l16(g, base + 24576 + tid * 8);
      g2l16(g + (size_t)64 * KB, base + 24576 + tid * 8 + 4096);
    } else if (h == 2) {
      const bf16* g = Ag + (size_t)srow * KA + t * 64 + scol;
      g2l16(g, base + tid * 8);
      g2l16(g + (size_t)128 * KA, base + tid * 8 + 8192);
    } else {
      const bf16* g = Ag + (size_t)(64 + srow) * KA + t * 64 + scol;
      g2l16(g, base + 4096 + tid * 8);
      g2l16(g + (size_t)128 * KA, base + 4096 + tid * 8 + 8192);
    }
  };

  f32x4 brf[2][4];
  auto phase = [&](int t, auto qc, int st, int sh, auto dsc, auto vmc) {
    constexpr int q = decltype(qc)::value;
    constexpr bool ds = decltype(dsc)::value;
    constexpr int vm = decltype(vmc)::value;
    const uint32_t bb = (t & 1) ? 65536u : 0u;
    f32x4 ar[4];
#pragma unroll
    for (int ks = 0; ks < 4; ++ks)
      ar[ks] = ds_read128(a_l + bb + (uint32_t)(q * 4096) + ckk[ks]);
    if constexpr (q == 0) {
#pragma unroll
      for (int nj = 0; nj < 2; ++nj)
#pragma unroll
        for (int ks = 0; ks < 4; ++ks)
          brf[nj][ks] = ds_read128(b_l + bb + (uint32_t)(nj * 4096) + ckk[ks]);
    }
    if constexpr (ds) stg(st, sh);
    __builtin_amdgcn_s_barrier();
    asm volatile("s_waitcnt lgkmcnt(0)" ::: "memory");
    __builtin_amdgcn_sched_barrier(0);
    __builtin_amdgcn_s_setprio(1);
#pragma unroll
    for (int ks = 0; ks < 4; ++ks)
#pragma unroll
      for (int nj = 0; nj < 2; ++nj)
        acc[q][nj] = __builtin_amdgcn_mfma_f32_32x32x16_bf16(
            __builtin_bit_cast(bf16x8, ar[ks]),
            __builtin_bit_cast(bf16x8, brf[nj][ks]),
            acc[q][nj], 0, 0, 0);
    __builtin_amdgcn_s_setprio(0);
    waitvm<vm>();
    __builtin_amdgcn_s_barrier();
  };

  stg(0, 0); stg(0, 1); stg(0, 2); stg(0, 3);
  stg(1, 0); stg(1, 1); stg(1, 2);
  asm volatile("s_waitcnt vmcnt(6)" ::: "memory");
  __builtin_amdgcn_s_barrier();

  constexpr int NI = NT / 2;
#pragma unroll 1
  for (int u = 0; u < NI - 1; ++u) {
    const int t0 = 2 * u, t1 = t0 + 1;
    phase(t0, IC<0>{}, t1, 3, BC<true>{}, IC<-1>{});
    phase(t0, IC<1>{}, t0 + 2, 0, BC<true>{}, IC<-1>{});
    phase(t0, IC<2>{}, t0 + 2, 1, BC<true>{}, IC<-1>{});
    phase(t0, IC<3>{}, t0 + 2, 2, BC<true>{}, IC<6>{});
    phase(t1, IC<0>{}, t0 + 2, 3, BC<true>{}, IC<-1>{});
    phase(t1, IC<1>{}, t0 + 3, 0, BC<true>{}, IC<-1>{});
    phase(t1, IC<2>{}, t0 + 3, 1, BC<true>{}, IC<-1>{});
    phase(t1, IC<3>{}, t0 + 3, 2, BC<true>{}, IC<6>{});
  }
  {
    const int t0 = NT - 2, t1 = NT - 1;
    phase(t0, IC<0>{}, t1, 3, BC<true>{}, IC<-1>{});
    phase(t0, IC<1>{}, 0, 0, BC<false>{}, IC<-1>{});
    phase(t0, IC<2>{}, 0, 0, BC<false>{}, IC<-1>{});
    phase(t0, IC<3>{}, 0, 0, BC<false>{}, IC<0>{});
    phase(t1, IC<0>{}, 0, 0, BC<false>{}, IC<-1>{});
    phase(t1, IC<1>{}, 0, 0, BC<false>{}, IC<-1>{});
    phase(t1, IC<2>{}, 0, 0, BC<false>{}, IC<-1>{});
    phase(t1, IC<3>{}, 0, 0, BC<false>{}, IC<-1>{});
  }
}

// ---------------- fused QKV GEMM (R7 structure, 32x32 MFMA) ----------------
// 1536 blocks, m-grouped XCD swizzle. 4 waves 2x2, wave tile 64x64 = 2x2
// frags of 32x32; 4 ksteps/K-tile, 16 MFMA (was 32 of 16x16).
__global__ __launch_bounds__(256, 2) void gemm_qkv(
    const bf16* __restrict__ Xb, const bf16* __restrict__ Wb3,
    const float* __restrict__ bq, const float* __restrict__ bk,
    const float* __restrict__ bv, bf16* __restrict__ QK,
    bf16* __restrict__ Vt)
{
  constexpr int K = 1024, N = 1024;
  __shared__ __align__(16) bf16 ldsA[128 * 64];
  __shared__ __align__(16) bf16 ldsB[128 * 64];

  const int tid  = threadIdx.x;
  const int lane = tid & 63;
  const int wave = tid >> 6;
  const int d = blockIdx.y * 64 + blockIdx.x;
  const int xcd = d & 7, slot = d >> 3;
  const int g = xcd * 8 + slot / 24;      // m-tile 0..63
  const int c3 = slot % 24;               // which*8 + n-tile
  const int which = c3 >> 3;
  const int n0 = (c3 & 7) * 128;
  const int m0 = g * 128;
  const bf16* Bt = Wb3 + (size_t)which * 1048576;
  const float* bias = (which == 0) ? bq : ((which == 1) ? bk : bv);

  const int l31 = lane & 31, hi = lane >> 5;
  const int wm = (wave >> 1) * 64;
  const int wn = (wave & 1) * 64;
  const int sw = l31 & 7;

  f32x16 acc[2][2];
#pragma unroll
  for (int i = 0; i < 2; ++i)
#pragma unroll
    for (int j = 0; j < 2; ++j) acc[i][j] = (f32x16)(0.f);

  const int srow = tid >> 3;
  const int scol = ((tid & 7) ^ (srow & 7)) * 8;
  const size_t a_base = (size_t)(m0 + srow) * K + scol;
  const size_t b_base = (size_t)(n0 + srow) * K + scol;
  const int lds_off = tid * 8;

  for (int kt = 0; kt < K; kt += 64) {
    const bf16* ga = Xb + a_base + kt;
    const bf16* gb = Bt + b_base + kt;
#pragma unroll
    for (int it = 0; it < 4; ++it) {
      g2l16(ga + (size_t)(it * 32) * K, &ldsA[lds_off + it * 2048]);
      g2l16(gb + (size_t)(it * 32) * K, &ldsB[lds_off + it * 2048]);
    }
    __syncthreads();
#pragma unroll
    for (int ks = 0; ks < 4; ++ks) {
      const int ch = (ks * 2 + hi) ^ sw;
      bf16x8 af[2], bfg[2];
#pragma unroll
      for (int mi = 0; mi < 2; ++mi)
        af[mi] = *(const bf16x8*)&ldsA[(wm + mi * 32 + l31) * 64 + ch * 8];
#pragma unroll
      for (int nj = 0; nj < 2; ++nj)
        bfg[nj] = *(const bf16x8*)&ldsB[(wn + nj * 32 + l31) * 64 + ch * 8];
#pragma unroll
      for (int mi = 0; mi < 2; ++mi)
#pragma unroll
        for (int nj = 0; nj < 2; ++nj)
          acc[mi][nj] = __builtin_amdgcn_mfma_f32_32x32x16_bf16(
              af[mi], bfg[nj], acc[mi][nj], 0, 0, 0);
    }
    __syncthreads();
  }

  // C/D layout: col = lane&31, row = (reg&3)+8*(reg>>2)+4*(lane>>5)
  if (which < 2) {
    bf16* C = QK + (size_t)which * (size_t)(8192 * 1024);
#pragma unroll
    for (int mi = 0; mi < 2; ++mi) {
      const int rb = m0 + wm + mi * 32 + 4 * hi;
#pragma unroll
      for (int nj = 0; nj < 2; ++nj) {
        const int cc = n0 + wn + nj * 32 + l31;
        const float bvv = bias[cc];
#pragma unroll
        for (int gq = 0; gq < 4; ++gq)
#pragma unroll
          for (int k = 0; k < 4; ++k)
            C[(size_t)(rb + 8 * gq + k) * N + cc] =
                (bf16)(acc[mi][nj][4 * gq + k] + bvv);
      }
    }
  } else {
#pragma unroll
    for (int mi = 0; mi < 2; ++mi) {
      const int rb = m0 + wm + mi * 32 + 4 * hi;
#pragma unroll
      for (int nj = 0; nj < 2; ++nj) {
        const int cc = n0 + wn + nj * 32 + l31;  // h
        const float bvv = bias[cc];
#pragma unroll
        for (int gq = 0; gq < 4; ++gq) {
          const int r0 = rb + 8 * gq;            // b*4096+s, 4-aligned
          const int b = r0 >> 12, s = r0 & 4095;
          bf16x4 o;
#pragma unroll
          for (int k = 0; k < 4; ++k) o[k] = (bf16)(acc[mi][nj][4 * gq + k] + bvv);
          *(bf16x4*)&Vt[((size_t)(b * 1024 + cc)) * 4096 + s] = o;
        }
      }
    }
  }
}

// ---------------- scores GEMM + fused exp/mask/partial-row-sum -------------
// grid (32, 16). psum[(by*4 + wave&3)][r] written exactly once (lane 0 and
// lane 32 cover disjoint row sets). Mask int32 in-epilogue (R11-proven).
__global__ __launch_bounds__(512, 2) void gemm_scores(
    const bf16* __restrict__ Q, const bf16* __restrict__ Kb,
    const int* __restrict__ mask, bf16* __restrict__ P,
    float* __restrict__ psum) {
  __shared__ __align__(16) bf16 lds[2 * 32768];  // 128 KiB
  const int bid = blockIdx.y * 32 + blockIdx.x;
  const int sb = (bid & 7) * 64 + (bid >> 3);
  const int bx = sb & 31, by = sb >> 5;
  const int m0 = bx * 256;
  const int n0 = by * 256;
  const int batch = m0 >> 12;
  const bf16* Ag = Q + (size_t)m0 * 1024;
  const bf16* Bg = Kb + (size_t)batch * (size_t)(4096 * 1024) +
                   (size_t)n0 * 1024;

  f32x16 acc[4][2];
#pragma unroll
  for (int i = 0; i < 4; ++i)
#pragma unroll
    for (int j = 0; j < 2; ++j) acc[i][j] = (f32x16)(0.f);

  kloop256<16>(Ag, Bg, 1024, 1024, lds, acc);

  const int lane = threadIdx.x & 63, wave = threadIdx.x >> 6;
  const int l31 = lane & 31, hi = lane >> 5;
  const int wrow = (wave >> 2) * 128, wcol = (wave & 3) * 64;
  float* ps = psum + (size_t)(by * 4 + (wave & 3)) * 8192;

#pragma unroll
  for (int mi = 0; mi < 4; ++mi) {
    const int rb = m0 + wrow + mi * 32 + 4 * hi;
    float rsum[16];
#pragma unroll
    for (int reg = 0; reg < 16; ++reg) rsum[reg] = 0.f;
#pragma unroll
    for (int nj = 0; nj < 2; ++nj) {
      const int c = n0 + wcol + nj * 32 + l31;
#pragma unroll
      for (int reg = 0; reg < 16; ++reg) {
        const int r = rb + (reg & 3) + 8 * (reg >> 2);
        float e = __expf(acc[mi][nj][reg] * 0.03125f);
        if (mask[(size_t)r * 4096 + c] == 0) e = 0.f;
        P[(size_t)r * 4096 + c] = (bf16)e;
        rsum[reg] += e;
      }
    }
    // reduce across the 32 column-lanes (stays within the hi-half)
#pragma unroll
    for (int off = 1; off < 32; off <<= 1) {
#pragma unroll
      for (int reg = 0; reg < 16; ++reg)
        rsum[reg] += __shfl_xor(rsum[reg], off);
    }
    if (l31 == 0) {
#pragma unroll
      for (int reg = 0; reg < 16; ++reg)
        ps[rb + (reg & 3) + 8 * (reg >> 2)] = rsum[reg];
    }
  }
}

// ---------------- PV GEMM (R7 structure, 32x32 MFMA) -----------------------
// 512 blocks, m-grouped XCD swizzle. Cooperative psum reduction epilogue.
__global__ __launch_bounds__(256, 2) void gemm_pv(
    const bf16* __restrict__ A, const bf16* __restrict__ Bt,
    const float* __restrict__ psum, float* __restrict__ C)
{
  constexpr int N = 1024, K = 4096;
  __shared__ __align__(16) bf16 ldsA[128 * 64];
  __shared__ __align__(16) bf16 ldsB[128 * 64];

  const int tid  = threadIdx.x;
  const int lane = tid & 63;
  const int wave = tid >> 6;
  const int d = blockIdx.y * 64 + blockIdx.x;
  const int xcd = d & 7, slot = d >> 3;
  const int g = xcd * 8 + (slot >> 3);   // m-tile 0..63
  const int h = slot & 7;                // n-tile 0..7
  const int m0 = g * 128;
  const int n0 = h * 128;
  const int batch = m0 >> 12;
  const bf16* Btb = Bt + (size_t)batch * (size_t)(1024 * 4096);

  const int l31 = lane & 31, hi = lane >> 5;
  const int wm = (wave >> 1) * 64;
  const int wn = (wave & 1) * 64;
  const int sw = l31 & 7;

  f32x16 acc[2][2];
#pragma unroll
  for (int i = 0; i < 2; ++i)
#pragma unroll
    for (int j = 0; j < 2; ++j) acc[i][j] = (f32x16)(0.f);

  const int srow = tid >> 3;
  const int scol = ((tid & 7) ^ (srow & 7)) * 8;
  const size_t a_base = (size_t)(m0 + srow) * K + scol;
  const size_t b_base = (size_t)(n0 + srow) * K + scol;
  const int lds_off = tid * 8;

  for (int kt = 0; kt < K; kt += 64) {
    const bf16* ga = A + a_base + kt;
    const bf16* gb = Btb + b_base + kt;
#pragma unroll
    for (int it = 0; it < 4; ++it) {
      g2l16(ga + (size_t)(it * 32) * K, &ldsA[lds_off + it * 2048]);
      g2l16(gb + (size_t)(it * 32) * K, &ldsB[lds_off + it * 2048]);
    }
    __syncthreads();
#pragma unroll
    for (int ks = 0; ks < 4; ++ks) {
      const int ch = (ks * 2 + hi) ^ sw;
      bf16x8 af[2], bfg[2];
#pragma unroll
      for (int mi = 0; mi < 2; ++mi)
        af[mi] = *(const bf16x8*)&ldsA[(wm + mi * 32 + l31) * 64 + ch * 8];
#pragma unroll
      for (int nj = 0; nj < 2; ++nj)
        bfg[nj] = *(const bf16x8*)&ldsB[(wn + nj * 32 + l31) * 64 + ch * 8];
#pragma unroll
      for (int mi = 0; mi < 2; ++mi)
#pragma unroll
        for (int nj = 0; nj < 2; ++nj)
          acc[mi][nj] = __builtin_amdgcn_mfma_f32_32x32x16_bf16(
              af[mi], bfg[nj], acc[mi][nj], 0, 0, 0);
    }
    __syncthreads();
  }

  // Cooperative row-sum reduction: 64 partials per row -> 1/sum in LDS.
  float* linv = (float*)ldsA;   // K-loop LDS dead (loop ends with barrier)
  if (tid < 128) {
    float s = 0.f;
#pragma unroll 8
    for (int p = 0; p < 64; ++p) s += psum[(size_t)p * 8192 + m0 + tid];
    linv[tid] = 1.0f / s;
  }
  __syncthreads();

#pragma unroll
  for (int mi = 0; mi < 2; ++mi) {
    const int lrb = wm + mi * 32 + 4 * hi;   // local row base
#pragma unroll
    for (int nj = 0; nj < 2; ++nj) {
      const int c = n0 + wn + nj * 32 + l31;
#pragma unroll
      for (int gq = 0; gq < 4; ++gq)
#pragma unroll
        for (int k = 0; k < 4; ++k) {
          const int lr = lrb + 8 * gq + k;
          C[(size_t)(m0 + lr) * N + c] = acc[mi][nj][4 * gq + k] * linv[lr];
        }
    }
  }
}

extern "C" void kernel_launch(void* const* d_in, const int* in_sizes, int n_in,
                              void* d_out, int out_size, void* d_ws,
                              size_t ws_size, hipStream_t stream) {
  const float* X   = (const float*)d_in[0];
  const int* mask  = (const int*)d_in[1];
  const float* Wq  = (const float*)d_in[2];
  const float* bq  = (const float*)d_in[3];
  const float* Wk  = (const float*)d_in[4];
  const float* bk  = (const float*)d_in[5];
  const float* Wv  = (const float*)d_in[6];
  const float* bv  = (const float*)d_in[7];
  float* out = (float*)d_out;

  // ws layout (128 MiB): [0,16M) Q  [16M,32M) K  [32M,48M) X_bf
  //   [48M,64M) Vt  [64M,128M) Sc/P (first 6 MiB aliased by W_bf, dead
  //   after qkv).  psum (2 MB, 64x8192 f32) aliases X_bf (dead after qkv;
  //   every slot written by scores before pv reads -> no init).
  const size_t QKV_ELEMS = (size_t)8192 * 1024;
  bf16* Q    = (bf16*)d_ws;
  bf16* Kb   = Q + QKV_ELEMS;
  bf16* X_bf = Kb + QKV_ELEMS;
  bf16* Vt   = X_bf + QKV_ELEMS;
  bf16* Sc   = Vt + QKV_ELEMS;
  bf16* W_bf = Sc;
  float* psum = (float*)X_bf;  // 64 * 8192 floats = 2 MB

  cvt_all<<<dim3(5632), dim3(256), 0, stream>>>(X, Wq, Wk, Wv, X_bf, W_bf);
  gemm_qkv<<<dim3(64, 24), dim3(256), 0, stream>>>(X_bf, W_bf, bq, bk, bv, Q,
                                                   Vt);
  gemm_scores<<<dim3(32, 16), dim3(512), 0, stream>>>(Q, Kb, mask, Sc, psum);
  gemm_pv<<<dim3(64, 8), dim3(256), 0, stream>>>(Sc, Vt, psum, out);
}